// Round 9
// baseline (213.020 us; speedup 1.0000x reference)
//
#include <hip/hip_runtime.h>
#include <cstdint>

typedef unsigned short u16;
typedef short v8s __attribute__((ext_vector_type(8)));
typedef u16   v8u __attribute__((ext_vector_type(8)));
typedef float v4f __attribute__((ext_vector_type(4)));

static __device__ __forceinline__ u16 f2b(float f) {
    unsigned u = __float_as_uint(f);
    unsigned r = (u + 0x7fffu + ((u >> 16) & 1u)) >> 16;
    return (u16)r;
}
static __device__ __forceinline__ float b2f(u16 u) {
    return __uint_as_float(((unsigned)u) << 16);
}

// QUARANTINE NOTE (R3/R4, reconfirmed R9): unrolled knn candidate loops ->
// deterministic wrong result. ALL candidate (c) loops carry an explicit
// `#pragma unroll 1`. No candidate register arrays.
// RULE-20 NOTE (R10): runtime-indexed register arrays -> scratch -> huge HBM
// traffic. All register arrays use compile-time indices only.
// WRITE-AMP NOTE (R13): scattered 4B out_att stores -> partial-line write
// amplification. out_att staged in LDS, written float4-coalesced.
// R15/R16: knn+attn FUSED — block owns 4 queries end-to-end; sorted neighbor
// keys pass through LDS (no global knn buffer); attn phase (1 query/wave)
// overlaps other blocks' VALU-bound knn phase on the same CU.
// (R16 = R15 verbatim resubmit: R15 failed with an infra-level
// "container failed twice" before any bench ran; testing flake hypothesis.)

// ---------------------------------------------------------------------------
// Kernel A (fused prep): blocks 0..255: x = feats@W1+b1; q/k/v (bf16);
// c4=[x,y,z,sq]. Blocks 256..258: Wp2/Wm1/Wm2 -> MFMA B-fragment order.
// Block 259: W2 transposed bf16.
// ---------------------------------------------------------------------------
__global__ __launch_bounds__(256) void prep_kernel(
    const float* __restrict__ feats, const float* __restrict__ coords,
    const float* __restrict__ W1, const float* __restrict__ b1,
    const float* __restrict__ Wq, const float* __restrict__ Wk, const float* __restrict__ Wv,
    const float* __restrict__ Wp2, const float* __restrict__ Wm1,
    const float* __restrict__ Wm2, const float* __restrict__ W2,
    u16* __restrict__ qb, u16* __restrict__ kb, u16* __restrict__ vb,
    float4* __restrict__ c4, u16* __restrict__ wfrag)
{
    const int tid = threadIdx.x;
    if (blockIdx.x >= 256) {
        int wb = blockIdx.x - 256;
        if (wb == 3) {
            for (int i = 0; i < 16; ++i) {
                int d = i * 256 + tid;       // d = l*64 + t
                int l = d >> 6, t = d & 63;
                wfrag[3 * 4096 + d] = f2b(W2[t * 64 + l]);
            }
        } else {
            const float* srcs[3] = {Wp2, Wm1, Wm2};
            const float* W = srcs[wb];
            for (int i = 0; i < 16; ++i) {
                int d = i * 256 + tid;      // 0..4095
                int f = d >> 9;
                int lane = (d >> 3) & 63;
                int j = d & 7;
                int k = (f >> 2) * 32 + (lane >> 4) * 8 + j;
                int n = (f & 3) * 16 + (lane & 15);
                wfrag[wb * 4096 + d] = f2b(W[k * 64 + n]);
            }
        }
        return;
    }

    __shared__ float sA[64 * 64];
    __shared__ float wB[64 * 64];
    __shared__ float xt[64 * 64];
    const int gp0 = blockIdx.x * 64;

    if (tid < 64) {
        int p = gp0 + tid;
        float x = coords[p * 3 + 0];
        float y = coords[p * 3 + 1];
        float z = coords[p * 3 + 2];
        float sq = __fadd_rn(__fadd_rn(__fmul_rn(x, x), __fmul_rn(y, y)), __fmul_rn(z, z));
        c4[p] = make_float4(x, y, z, sq);
    }

    #pragma unroll
    for (int i = 0; i < 4; ++i) {
        int chunk = i * 256 + tid;          // 1024 chunks of 4 floats
        ((float4*)sA)[chunk] = ((const float4*)(feats + (size_t)gp0 * 64))[chunk];
        ((float4*)wB)[chunk] = ((const float4*)W1)[chunk];
    }
    __syncthreads();

    const int tx = tid & 15, py = tid >> 4;
    const int c0 = tx * 4, p0 = py * 4;

    {
        float acc[4][4] = {};
        for (int k = 0; k < 64; ++k) {
            float a_[4], w_[4];
            #pragma unroll
            for (int i = 0; i < 4; ++i) a_[i] = sA[(p0 + i) * 64 + k];
            #pragma unroll
            for (int j = 0; j < 4; ++j) w_[j] = wB[k * 64 + c0 + j];
            #pragma unroll
            for (int i = 0; i < 4; ++i)
                #pragma unroll
                for (int j = 0; j < 4; ++j)
                    acc[i][j] = fmaf(a_[i], w_[j], acc[i][j]);
        }
        float bs[4];
        #pragma unroll
        for (int j = 0; j < 4; ++j) bs[j] = b1[c0 + j];
        #pragma unroll
        for (int i = 0; i < 4; ++i)
            #pragma unroll
            for (int j = 0; j < 4; ++j)
                xt[(p0 + i) * 64 + c0 + j] = acc[i][j] + bs[j];
    }
    __syncthreads();

    const float* Ws[3] = {Wq, Wk, Wv};
    u16* Os[3] = {qb, kb, vb};
    for (int mtx = 0; mtx < 3; ++mtx) {
        #pragma unroll
        for (int i = 0; i < 4; ++i) {
            int chunk = i * 256 + tid;
            ((float4*)wB)[chunk] = ((const float4*)Ws[mtx])[chunk];
        }
        __syncthreads();
        float acc[4][4] = {};
        for (int k = 0; k < 64; ++k) {
            float a_[4], w_[4];
            #pragma unroll
            for (int i = 0; i < 4; ++i) a_[i] = xt[(p0 + i) * 64 + k];
            #pragma unroll
            for (int j = 0; j < 4; ++j) w_[j] = wB[k * 64 + c0 + j];
            #pragma unroll
            for (int i = 0; i < 4; ++i)
                #pragma unroll
                for (int j = 0; j < 4; ++j)
                    acc[i][j] = fmaf(a_[i], w_[j], acc[i][j]);
        }
        #pragma unroll
        for (int i = 0; i < 4; ++i) {
            ushort4 st;
            st.x = f2b(acc[i][0]); st.y = f2b(acc[i][1]);
            st.z = f2b(acc[i][2]); st.w = f2b(acc[i][3]);
            *(ushort4*)(Os[mtx] + (size_t)(gp0 + p0 + i) * 64 + c0) = st;
        }
        __syncthreads();
    }
}

// ---------------------------------------------------------------------------
// Kernel B: FUSED exact-KNN + attention. knn part = R11-verbatim (hardware-
// proven); final bitonic keys go to LDS idxbuf instead of global. attn part
// = R14 body specialized to 1 query/wave (vw-fold + coalesced out_att),
// wave wv owns query q0+wv for both phases. LDS reuse: attn's pos/g/att
// staging region aliases the dead knn scratchf wave-region (wave-local after
// the post-Pass-B barrier; 1088 floats/wave >= 1024 needed).
// ---------------------------------------------------------------------------
__global__ __launch_bounds__(256, 4) void knn_attn_kernel(
    const float4* __restrict__ c4,
    const u16* __restrict__ qb, const u16* __restrict__ kb, const u16* __restrict__ vb,
    const u16* __restrict__ wfrag,
    const float* __restrict__ Wp1, const float* __restrict__ bp1, const float* __restrict__ bp2,
    const float* __restrict__ bm1, const float* __restrict__ bm2,
    const float* __restrict__ b2,
    const float* __restrict__ feats,
    float* __restrict__ out0, float* __restrict__ out_att)
{
    // scratchf overlay:
    //   knn A/T : emin[s][w*64+lane] = first 1024 floats
    //   knn fb  : per-wave lists, wave wv uses scratchf + wv*1088 (17*64)
    //   attn    : wave wv region scratchf + wv*1088: pgbuf(576f as u16),
    //             then att staging (1024f), then obuf (64f) — wave-local.
    __shared__ __align__(16) float scratchf[4 * 17 * 64];
    __shared__ unsigned long long keybuf[4][64];
    __shared__ int cnt[4];
    __shared__ float Tsh[4];
    __shared__ float relbuf[4][16][4];
    __shared__ int   idxbuf[4][16];

    const int tid = threadIdx.x;
    const int lane = tid & 63, wv = tid >> 6;
    const int q0 = blockIdx.x * 4;                 // this block's 4 queries
    const int bb = q0 >> 12;                       // 4 | 4096 -> same batch
    const float4* cb = c4 + ((size_t)bb << 12);
    const int cbase = wv * 16;                     // this wave's candidate rows

    // ---------------- knn phase (R11-verbatim) ----------------
    float4 cq0 = cb[(q0 & 4095) + 0];
    float4 cq1 = cb[(q0 & 4095) + 1];
    float4 cq2 = cb[(q0 & 4095) + 2];
    float4 cq3 = cb[(q0 & 4095) + 3];
    float e0 = __builtin_inff(), e1 = __builtin_inff();
    float e2 = __builtin_inff(), e3 = __builtin_inff();

    // Pass A: per-lane cell-min over this wave's 16 candidate rows. ROLLED.
    #pragma unroll 1
    for (int c = 0; c < 16; ++c) {
        float4 cj = cb[(cbase + c) * 64 + lane];
        {
            float dot = __fadd_rn(__fadd_rn(__fmul_rn(cq0.x, cj.x), __fmul_rn(cq0.y, cj.y)),
                                  __fmul_rn(cq0.z, cj.z));
            float d = __fsub_rn(__fadd_rn(cq0.w, cj.w), __fmul_rn(2.0f, dot));
            e0 = fminf(e0, d);
        }
        {
            float dot = __fadd_rn(__fadd_rn(__fmul_rn(cq1.x, cj.x), __fmul_rn(cq1.y, cj.y)),
                                  __fmul_rn(cq1.z, cj.z));
            float d = __fsub_rn(__fadd_rn(cq1.w, cj.w), __fmul_rn(2.0f, dot));
            e1 = fminf(e1, d);
        }
        {
            float dot = __fadd_rn(__fadd_rn(__fmul_rn(cq2.x, cj.x), __fmul_rn(cq2.y, cj.y)),
                                  __fmul_rn(cq2.z, cj.z));
            float d = __fsub_rn(__fadd_rn(cq2.w, cj.w), __fmul_rn(2.0f, dot));
            e2 = fminf(e2, d);
        }
        {
            float dot = __fadd_rn(__fadd_rn(__fmul_rn(cq3.x, cj.x), __fmul_rn(cq3.y, cj.y)),
                                  __fmul_rn(cq3.z, cj.z));
            float d = __fsub_rn(__fadd_rn(cq3.w, cj.w), __fmul_rn(2.0f, dot));
            e3 = fminf(e3, d);
        }
    }
    scratchf[0 * 256 + wv * 64 + lane] = e0;
    scratchf[1 * 256 + wv * 64 + lane] = e1;
    scratchf[2 * 256 + wv * 64 + lane] = e2;
    scratchf[3 * 256 + wv * 64 + lane] = e3;
    __syncthreads();

    // Wave wv: T for query wv = 16th smallest of the 64 combined lane-minima.
    {
        const float* em = scratchf + wv * 256;
        float v = fminf(fminf(em[lane], em[64 + lane]),
                        fminf(em[128 + lane], em[192 + lane]));
        #pragma unroll
        for (int k = 2; k <= 64; k <<= 1) {
            #pragma unroll
            for (int j = k >> 1; j > 0; j >>= 1) {
                float o = __shfl_xor(v, j, 64);
                bool up = ((lane & k) == 0);
                bool lower = ((lane & j) == 0);
                bool takemin = (lower == up);
                bool oless = (o < v);
                v = (takemin == oless) ? o : v;
            }
        }
        float Tq = __shfl(v, 15, 64);
        if (lane == 0) { Tsh[wv] = Tq; cnt[wv] = 0; }
    }
    __syncthreads();

    const float T0 = Tsh[0], T1 = Tsh[1], T2 = Tsh[2], T3 = Tsh[3];

    // Pass B: this wave's 16 rows, all 4 queries; survivors via block atomics.
    // ROLLED.
    #pragma unroll 1
    for (int c = 0; c < 16; ++c) {
        float4 cj = cb[(cbase + c) * 64 + lane];
        unsigned idx = (unsigned)((cbase + c) * 64 + lane);
        {
            float dot = __fadd_rn(__fadd_rn(__fmul_rn(cq0.x, cj.x), __fmul_rn(cq0.y, cj.y)),
                                  __fmul_rn(cq0.z, cj.z));
            float d = __fsub_rn(__fadd_rn(cq0.w, cj.w), __fmul_rn(2.0f, dot));
            if (d <= T0) {
                int pos = atomicAdd(&cnt[0], 1);
                if (pos < 64) {
                    unsigned u = __float_as_uint(d);
                    unsigned ord = (u & 0x80000000u) ? ~u : (u | 0x80000000u);
                    keybuf[0][pos] = ((unsigned long long)ord << 32) | idx;
                }
            }
        }
        {
            float dot = __fadd_rn(__fadd_rn(__fmul_rn(cq1.x, cj.x), __fmul_rn(cq1.y, cj.y)),
                                  __fmul_rn(cq1.z, cj.z));
            float d = __fsub_rn(__fadd_rn(cq1.w, cj.w), __fmul_rn(2.0f, dot));
            if (d <= T1) {
                int pos = atomicAdd(&cnt[1], 1);
                if (pos < 64) {
                    unsigned u = __float_as_uint(d);
                    unsigned ord = (u & 0x80000000u) ? ~u : (u | 0x80000000u);
                    keybuf[1][pos] = ((unsigned long long)ord << 32) | idx;
                }
            }
        }
        {
            float dot = __fadd_rn(__fadd_rn(__fmul_rn(cq2.x, cj.x), __fmul_rn(cq2.y, cj.y)),
                                  __fmul_rn(cq2.z, cj.z));
            float d = __fsub_rn(__fadd_rn(cq2.w, cj.w), __fmul_rn(2.0f, dot));
            if (d <= T2) {
                int pos = atomicAdd(&cnt[2], 1);
                if (pos < 64) {
                    unsigned u = __float_as_uint(d);
                    unsigned ord = (u & 0x80000000u) ? ~u : (u | 0x80000000u);
                    keybuf[2][pos] = ((unsigned long long)ord << 32) | idx;
                }
            }
        }
        {
            float dot = __fadd_rn(__fadd_rn(__fmul_rn(cq3.x, cj.x), __fmul_rn(cq3.y, cj.y)),
                                  __fmul_rn(cq3.z, cj.z));
            float d = __fsub_rn(__fadd_rn(cq3.w, cj.w), __fmul_rn(2.0f, dot));
            if (d <= T3) {
                int pos = atomicAdd(&cnt[3], 1);
                if (pos < 64) {
                    unsigned u = __float_as_uint(d);
                    unsigned ord = (u & 0x80000000u) ? ~u : (u | 0x80000000u);
                    keybuf[3][pos] = ((unsigned long long)ord << 32) | idx;
                }
            }
        }
    }
    __syncthreads();
    // After this barrier, scratchf/keybuf use is wave-local only.

    // Epilogue: wave wv owns query wv. Reload cqs from global (L2-hot).
    const float4 cqs = cb[(q0 & 4095) + wv];
    int cn = cnt[wv];
    if (cn > 64) {
        // Exact fallback (wave-uniform branch; wave-local state; no barriers).
        float* lists = scratchf + wv * 1088;   // emin region dead by now
        float dist[16];
        #pragma unroll
        for (int i = 0; i < 16; ++i) dist[i] = __builtin_inff();
        #pragma unroll 1
        for (int c = 0; c < 64; ++c) {
            float4 cj = cb[c * 64 + lane];
            float dot = __fadd_rn(__fadd_rn(__fmul_rn(cqs.x, cj.x), __fmul_rn(cqs.y, cj.y)),
                                  __fmul_rn(cqs.z, cj.z));
            float d = __fsub_rn(__fadd_rn(cqs.w, cj.w), __fmul_rn(2.0f, dot));
            #pragma unroll
            for (int i = 15; i > 0; --i)
                dist[i] = __builtin_amdgcn_fmed3f(dist[i - 1], d, dist[i]);
            dist[0] = fminf(dist[0], d);
        }
        #pragma unroll
        for (int i = 0; i < 16; ++i) lists[lane * 17 + i] = dist[i];

        float h2 = dist[0];
        int p2 = 0;
        float d16 = 0.0f;
        for (int it = 0; it < 16; ++it) {
            float m2 = h2;
            #pragma unroll
            for (int off = 32; off > 0; off >>= 1) m2 = fminf(m2, __shfl_xor(m2, off, 64));
            unsigned long long msk = __ballot(h2 == m2);
            int first = __ffsll((unsigned long long)msk) - 1;
            if (lane == first) {
                p2++;
                h2 = (p2 < 16) ? lists[lane * 17 + p2] : __builtin_inff();
            }
            d16 = m2;
        }

        if (lane == 0) cnt[wv] = 0;   // same-wave ds ordering: reset precedes atomics
        #pragma unroll 1
        for (int c = 0; c < 64; ++c) {
            float4 cj = cb[c * 64 + lane];
            float dot = __fadd_rn(__fadd_rn(__fmul_rn(cqs.x, cj.x), __fmul_rn(cqs.y, cj.y)),
                                  __fmul_rn(cqs.z, cj.z));
            float d = __fsub_rn(__fadd_rn(cqs.w, cj.w), __fmul_rn(2.0f, dot));
            if (d <= d16) {
                int pos = atomicAdd(&cnt[wv], 1);
                if (pos < 64) {
                    unsigned u = __float_as_uint(d);
                    unsigned ord = (u & 0x80000000u) ? ~u : (u | 0x80000000u);
                    keybuf[wv][pos] =
                        ((unsigned long long)ord << 32) | (unsigned)(c * 64 + lane);
                }
            }
        }
        cn = cnt[wv];
    }

    int mcount = cn < 64 ? cn : 64;
    unsigned long long key = (lane < mcount) ? keybuf[wv][lane] : ~0ull;
    // 64-lane bitonic sort ascending on (d, idx).
    #pragma unroll
    for (int k = 2; k <= 64; k <<= 1) {
        #pragma unroll
        for (int j = k >> 1; j > 0; j >>= 1) {
            unsigned long long o = __shfl_xor(key, j, 64);
            bool up = ((lane & k) == 0);
            bool lower = ((lane & j) == 0);
            bool takemin = (lower == up);
            bool oless = (o < key);
            key = (takemin == oless) ? o : key;
        }
    }

    // ---------------- attn phase (wave-local; R14 body, 1 query) ----------
    const int q = q0 + wv;
    const int col = lane & 15, quad = lane >> 4;
    const int m = col;

    if (lane < 16) {
        int jj = (int)(unsigned)(key & 0xffffffffull) & 4095;
        idxbuf[wv][lane] = jj;
        float4 cj = cb[jj];
        float4 cn2 = cb[q & 4095];
        relbuf[wv][lane][0] = cn2.x - cj.x;
        relbuf[wv][lane][1] = cn2.y - cj.y;
        relbuf[wv][lane][2] = cn2.z - cj.z;
    }
    // same-wave LDS handoff: no barrier needed.

    // V prefetch (latency hides under t/pos phases). Static indices only.
    float vpre[4][4];   // [r][nt]
    #pragma unroll
    for (int r = 0; r < 4; ++r) {
        int jr = idxbuf[wv][quad * 4 + r];
        const u16* vp = vb + (size_t)((bb << 12) + jr) * 64;
        #pragma unroll
        for (int nt = 0; nt < 4; ++nt)
            vpre[r][nt] = b2f(vp[nt * 16 + col]);
    }

    const float r0 = relbuf[wv][m][0], r1 = relbuf[wv][m][1], r2 = relbuf[wv][m][2];

    // t = relu(rel @ Wp1 + bp1), built directly in A-fragment layout.
    v8s a0, a1;
    #pragma unroll
    for (int hh = 0; hh < 2; ++hh) {
        int tb = hh * 32 + quad * 8;
        #pragma unroll
        for (int j = 0; j < 8; ++j) {
            float t = bp1[tb + j];
            t = fmaf(r0, Wp1[0 * 64 + tb + j], t);
            t = fmaf(r1, Wp1[1 * 64 + tb + j], t);
            t = fmaf(r2, Wp1[2 * 64 + tb + j], t);
            t = fmaxf(t, 0.0f);
            if (hh == 0) a0[j] = (short)f2b(t); else a1[j] = (short)f2b(t);
        }
    }

    // pos = t @ Wp2 + bp2 (C-layout); vw = v + pos folded immediately.
    float* wreg = scratchf + wv * 1088;       // wave-local union region
    float vw[4][4];                           // [r][nt]
    #pragma unroll
    for (int nt = 0; nt < 4; ++nt) {
        float bias = bp2[nt * 16 + col];
        v4f acc = {bias, bias, bias, bias};
        v8s bf0 = *(const v8s*)(wfrag + (0 + nt) * 512 + lane * 8);
        v8s bf1 = *(const v8s*)(wfrag + (4 + nt) * 512 + lane * 8);
        acc = __builtin_amdgcn_mfma_f32_16x16x32_bf16(a0, bf0, acc, 0, 0, 0);
        acc = __builtin_amdgcn_mfma_f32_16x16x32_bf16(a1, bf1, acc, 0, 0, 0);
        u16* pg = (u16*)wreg;
        #pragma unroll
        for (int r = 0; r < 4; ++r) {
            pg[(quad * 4 + r) * 72 + nt * 16 + col] = f2b(acc[r]);
            vw[r][nt] = vpre[r][nt] + acc[r];
        }
    }

    // h = q - k + pos in A-layout (bf16 inputs).
    const int jm = idxbuf[wv][m];
    const u16* qp = qb + (size_t)q * 64;
    const u16* kp = kb + (size_t)((bb << 12) + jm) * 64;
    v8s ha0, ha1;
    #pragma unroll
    for (int hh = 0; hh < 2; ++hh) {
        int tb = hh * 32 + quad * 8;
        v8u qv = *(const v8u*)(qp + tb);
        v8u kv = *(const v8u*)(kp + tb);
        v8u pv = *(const v8u*)((const u16*)wreg + m * 72 + tb);
        #pragma unroll
        for (int j = 0; j < 8; ++j) {
            float hv = b2f(qv[j]) - b2f(kv[j]) + b2f(pv[j]);
            if (hh == 0) ha0[j] = (short)f2b(hv); else ha1[j] = (short)f2b(hv);
        }
    }

    // g = relu(h @ Wm1 + bm1) -> pgbuf (WAR vs pv reads: same-wave order).
    #pragma unroll
    for (int nt = 0; nt < 4; ++nt) {
        float bias = bm1[nt * 16 + col];
        v4f acc = {bias, bias, bias, bias};
        v8s bf0 = *(const v8s*)(wfrag + 4096 + (0 + nt) * 512 + lane * 8);
        v8s bf1 = *(const v8s*)(wfrag + 4096 + (4 + nt) * 512 + lane * 8);
        acc = __builtin_amdgcn_mfma_f32_16x16x32_bf16(ha0, bf0, acc, 0, 0, 0);
        acc = __builtin_amdgcn_mfma_f32_16x16x32_bf16(ha1, bf1, acc, 0, 0, 0);
        u16* pg = (u16*)wreg;
        #pragma unroll
        for (int r = 0; r < 4; ++r)
            pg[(quad * 4 + r) * 72 + nt * 16 + col] = f2b(fmaxf(acc[r], 0.0f));
    }

    // ga fragments; pgbuf dead after this.
    v8s ga0 = *(const v8s*)((const u16*)wreg + m * 72 + quad * 8);
    v8s ga1 = *(const v8s*)((const u16*)wreg + m * 72 + 32 + quad * 8);

    // att = g @ Wm2 + bm2, fused softmax; att staged in LDS (over dead pgbuf)
    // for coalesced global write.
    float o4[4];
    #pragma unroll
    for (int nt = 0; nt < 4; ++nt) {
        float bias = bm2[nt * 16 + col];
        v4f acc = {bias, bias, bias, bias};
        v8s bf0 = *(const v8s*)(wfrag + 8192 + (0 + nt) * 512 + lane * 8);
        v8s bf1 = *(const v8s*)(wfrag + 8192 + (4 + nt) * 512 + lane * 8);
        acc = __builtin_amdgcn_mfma_f32_16x16x32_bf16(ga0, bf0, acc, 0, 0, 0);
        acc = __builtin_amdgcn_mfma_f32_16x16x32_bf16(ga1, bf1, acc, 0, 0, 0);

        float s[4];
        #pragma unroll
        for (int r = 0; r < 4; ++r) s[r] = acc[r] * 0.125f;
        float mx = fmaxf(fmaxf(s[0], s[1]), fmaxf(s[2], s[3]));
        mx = fmaxf(mx, __shfl_xor(mx, 16, 64));
        mx = fmaxf(mx, __shfl_xor(mx, 32, 64));
        float e[4], sum = 0.0f;
        #pragma unroll
        for (int r = 0; r < 4; ++r) { e[r] = __expf(s[r] - mx); sum += e[r]; }
        sum += __shfl_xor(sum, 16, 64);
        sum += __shfl_xor(sum, 32, 64);
        float inv = 1.0f / sum;

        float o = 0.0f;
        #pragma unroll
        for (int r = 0; r < 4; ++r) {
            float a = e[r] * inv;
            wreg[(quad * 4 + r) * 64 + nt * 16 + col] = a;
            o = fmaf(a, vw[r][nt], o);
        }
        o += __shfl_xor(o, 16, 64);
        o += __shfl_xor(o, 32, 64);
        o4[nt] = o;
    }
    // same-wave LDS handoff: all att ds_writes precede the reads below.

    // out_att: coalesced float4 stores, each 64B line written once.
    {
        float* dst = out_att + (size_t)q * 1024;
        #pragma unroll
        for (int chunk = 0; chunk < 4; ++chunk) {
            float4 v4 = *(const float4*)&wreg[chunk * 256 + lane * 4];
            *(float4*)&dst[chunk * 256 + lane * 4] = v4;
        }
    }

    // obuf alias over dead att staging.
    if (quad == 0) {
        #pragma unroll
        for (int nt = 0; nt < 4; ++nt) wreg[nt * 16 + col] = o4[nt];
    }
    // same-wave LDS handoff: no barrier needed.

    // out = o @ W2 + b2 + features   (W2bt: bf16, transposed, L1/L2-hot)
    const u16* wrow = wfrag + 3 * 4096 + lane * 64;
    v8u w8[8];
    #pragma unroll
    for (int c = 0; c < 8; ++c) w8[c] = *(const v8u*)(wrow + c * 8);
    float acc = b2[lane] + feats[(size_t)q * 64 + lane];
    #pragma unroll
    for (int c = 0; c < 16; ++c) {
        float4 ov = *(const float4*)&wreg[c * 4];
        acc = fmaf(ov.x, b2f(w8[c >> 1][(c & 1) * 4 + 0]), acc);
        acc = fmaf(ov.y, b2f(w8[c >> 1][(c & 1) * 4 + 1]), acc);
        acc = fmaf(ov.z, b2f(w8[c >> 1][(c & 1) * 4 + 2]), acc);
        acc = fmaf(ov.w, b2f(w8[c >> 1][(c & 1) * 4 + 3]), acc);
    }
    out0[(size_t)q * 64 + lane] = acc;
}

// ---------------------------------------------------------------------------
extern "C" void kernel_launch(void* const* d_in, const int* in_sizes, int n_in,
                              void* d_out, int out_size, void* d_ws, size_t ws_size,
                              hipStream_t stream)
{
    (void)in_sizes; (void)n_in; (void)out_size; (void)ws_size;
    const float* coords = (const float*)d_in[0];
    const float* feats  = (const float*)d_in[1];
    const float* W1  = (const float*)d_in[2];
    const float* b1  = (const float*)d_in[3];
    const float* Wq  = (const float*)d_in[4];
    const float* Wk  = (const float*)d_in[5];
    const float* Wv  = (const float*)d_in[6];
    const float* Wm1 = (const float*)d_in[7];
    const float* bm1 = (const float*)d_in[8];
    const float* Wm2 = (const float*)d_in[9];
    const float* bm2 = (const float*)d_in[10];
    const float* Wp1 = (const float*)d_in[11];
    const float* bp1 = (const float*)d_in[12];
    const float* Wp2 = (const float*)d_in[13];
    const float* bp2 = (const float*)d_in[14];
    const float* W2  = (const float*)d_in[15];
    const float* b2  = (const float*)d_in[16];

    char* ws = (char*)d_ws;
    u16*    qb    = (u16*)(ws);
    u16*    kb    = (u16*)(ws + (4u << 20));
    u16*    vb    = (u16*)(ws + (8u << 20));
    float4* c4    = (float4*)(ws + (12u << 20));
    u16*    wfrag = (u16*)(ws + (12u << 20) + (256u << 10) + (1u << 20));

    float* out0    = (float*)d_out;
    float* out_att = out0 + (size_t)4 * 4096 * 64;

    prep_kernel<<<260, 256, 0, stream>>>(feats, coords, W1, b1, Wq, Wk, Wv,
                                         Wp2, Wm1, Wm2, W2,
                                         qb, kb, vb, c4, wfrag);
    knn_attn_kernel<<<4096, 256, 0, stream>>>(c4, qb, kb, vb, wfrag,
                                              Wp1, bp1, bp2, bm1, bm2, b2, feats,
                                              out0, out_att);
}

// Round 10
// 193.560 us; speedup vs baseline: 1.1005x; 1.1005x over previous
//
#include <hip/hip_runtime.h>
#include <cstdint>

typedef unsigned short u16;
typedef short v8s __attribute__((ext_vector_type(8)));
typedef u16   v8u __attribute__((ext_vector_type(8)));
typedef float v4f __attribute__((ext_vector_type(4)));

static __device__ __forceinline__ u16 f2b(float f) {
    unsigned u = __float_as_uint(f);
    unsigned r = (u + 0x7fffu + ((u >> 16) & 1u)) >> 16;
    return (u16)r;
}
static __device__ __forceinline__ float b2f(u16 u) {
    return __uint_as_float(((unsigned)u) << 16);
}

// QUARANTINE NOTE (R3/R4, reconfirmed R9): unrolled knn candidate loops ->
// deterministic wrong result. ALL candidate (c) loops carry an explicit
// `#pragma unroll 1`. No candidate register arrays.
// RULE-20 NOTE (R10): runtime-indexed register arrays (cq[wv]) -> scratch ->
// 96 MB/dispatch HBM. All register arrays below use compile-time indices
// only (fully-unrolled loops).
// WRITE-AMP NOTE (R13): scattered 4B out_att stores + long-lived pos_c ->
// WRITE_SIZE 69.6->98 MB. R14 stages att in LDS, writes float4-coalesced;
// pos folded into vw=v+pos immediately.
// FUSION NOTE (R15/R16): fusing knn+attn into one kernel REGRESSED
// (109.6 us vs 93 split): attn's LDS/VGPR footprint cut the VALU-bound knn
// phase's occupancy 65%->40%. Do NOT fuse phases with conflicting resource
// regimes. R17 = R14 split + W2-epilogue 4-accumulator chain split.

// ---------------------------------------------------------------------------
// Kernel A (fused): blocks 0..255: x = feats@W1+b1; q/k/v = x@W{q,k,v} (bf16);
// c4=[x,y,z,sq]. Blocks 256..258: Wp2/Wm1/Wm2 -> MFMA B-fragment order.
// Block 259: W2 transposed bf16.
// ---------------------------------------------------------------------------
__global__ __launch_bounds__(256) void prep_kernel(
    const float* __restrict__ feats, const float* __restrict__ coords,
    const float* __restrict__ W1, const float* __restrict__ b1,
    const float* __restrict__ Wq, const float* __restrict__ Wk, const float* __restrict__ Wv,
    const float* __restrict__ Wp2, const float* __restrict__ Wm1,
    const float* __restrict__ Wm2, const float* __restrict__ W2,
    u16* __restrict__ qb, u16* __restrict__ kb, u16* __restrict__ vb,
    float4* __restrict__ c4, u16* __restrict__ wfrag)
{
    const int tid = threadIdx.x;
    if (blockIdx.x >= 256) {
        int wb = blockIdx.x - 256;
        if (wb == 3) {
            for (int i = 0; i < 16; ++i) {
                int d = i * 256 + tid;       // d = l*64 + t
                int l = d >> 6, t = d & 63;
                wfrag[3 * 4096 + d] = f2b(W2[t * 64 + l]);
            }
        } else {
            const float* srcs[3] = {Wp2, Wm1, Wm2};
            const float* W = srcs[wb];
            for (int i = 0; i < 16; ++i) {
                int d = i * 256 + tid;      // 0..4095
                int f = d >> 9;
                int lane = (d >> 3) & 63;
                int j = d & 7;
                int k = (f >> 2) * 32 + (lane >> 4) * 8 + j;
                int n = (f & 3) * 16 + (lane & 15);
                wfrag[wb * 4096 + d] = f2b(W[k * 64 + n]);
            }
        }
        return;
    }

    __shared__ float sA[64 * 64];
    __shared__ float wB[64 * 64];
    __shared__ float xt[64 * 64];
    const int gp0 = blockIdx.x * 64;

    if (tid < 64) {
        int p = gp0 + tid;
        float x = coords[p * 3 + 0];
        float y = coords[p * 3 + 1];
        float z = coords[p * 3 + 2];
        float sq = __fadd_rn(__fadd_rn(__fmul_rn(x, x), __fmul_rn(y, y)), __fmul_rn(z, z));
        c4[p] = make_float4(x, y, z, sq);
    }

    #pragma unroll
    for (int i = 0; i < 4; ++i) {
        int chunk = i * 256 + tid;          // 1024 chunks of 4 floats
        ((float4*)sA)[chunk] = ((const float4*)(feats + (size_t)gp0 * 64))[chunk];
        ((float4*)wB)[chunk] = ((const float4*)W1)[chunk];
    }
    __syncthreads();

    const int tx = tid & 15, py = tid >> 4;
    const int c0 = tx * 4, p0 = py * 4;

    {
        float acc[4][4] = {};
        for (int k = 0; k < 64; ++k) {
            float a_[4], w_[4];
            #pragma unroll
            for (int i = 0; i < 4; ++i) a_[i] = sA[(p0 + i) * 64 + k];
            #pragma unroll
            for (int j = 0; j < 4; ++j) w_[j] = wB[k * 64 + c0 + j];
            #pragma unroll
            for (int i = 0; i < 4; ++i)
                #pragma unroll
                for (int j = 0; j < 4; ++j)
                    acc[i][j] = fmaf(a_[i], w_[j], acc[i][j]);
        }
        float bs[4];
        #pragma unroll
        for (int j = 0; j < 4; ++j) bs[j] = b1[c0 + j];
        #pragma unroll
        for (int i = 0; i < 4; ++i)
            #pragma unroll
            for (int j = 0; j < 4; ++j)
                xt[(p0 + i) * 64 + c0 + j] = acc[i][j] + bs[j];
    }
    __syncthreads();

    const float* Ws[3] = {Wq, Wk, Wv};
    u16* Os[3] = {qb, kb, vb};
    for (int mtx = 0; mtx < 3; ++mtx) {
        #pragma unroll
        for (int i = 0; i < 4; ++i) {
            int chunk = i * 256 + tid;
            ((float4*)wB)[chunk] = ((const float4*)Ws[mtx])[chunk];
        }
        __syncthreads();
        float acc[4][4] = {};
        for (int k = 0; k < 64; ++k) {
            float a_[4], w_[4];
            #pragma unroll
            for (int i = 0; i < 4; ++i) a_[i] = xt[(p0 + i) * 64 + k];
            #pragma unroll
            for (int j = 0; j < 4; ++j) w_[j] = wB[k * 64 + c0 + j];
            #pragma unroll
            for (int i = 0; i < 4; ++i)
                #pragma unroll
                for (int j = 0; j < 4; ++j)
                    acc[i][j] = fmaf(a_[i], w_[j], acc[i][j]);
        }
        #pragma unroll
        for (int i = 0; i < 4; ++i) {
            ushort4 st;
            st.x = f2b(acc[i][0]); st.y = f2b(acc[i][1]);
            st.z = f2b(acc[i][2]); st.w = f2b(acc[i][3]);
            *(ushort4*)(Os[mtx] + (size_t)(gp0 + p0 + i) * 64 + c0) = st;
        }
        __syncthreads();
    }
}

// ---------------------------------------------------------------------------
// Kernel B: exact KNN — R11-verbatim (hardware-proven).
// ---------------------------------------------------------------------------
__global__ __launch_bounds__(256) void knn_kernel(
    const float4* __restrict__ c4, int* __restrict__ knn)
{
    // scratchf overlay:
    //   phase A/T: emin[s][w*64+lane] = first 1024 floats (s*256 + w*64 + lane)
    //   fallback : per-wave lists, wave wv uses scratchf + wv*1088 (17*64)
    __shared__ float scratchf[4 * 17 * 64];
    __shared__ unsigned long long keybuf[4][64];
    __shared__ int cnt[4];
    __shared__ float Tsh[4];

    const int tid = threadIdx.x;
    const int lane = tid & 63, wv = tid >> 6;
    const int q0 = blockIdx.x * 4;                 // this block's 4 queries
    const int b = q0 >> 12;                        // 4 | 4096 -> same batch
    const float4* cb = c4 + ((size_t)b << 12);
    const int cbase = wv * 16;                     // this wave's candidate rows

    float4 cq0 = cb[(q0 & 4095) + 0];
    float4 cq1 = cb[(q0 & 4095) + 1];
    float4 cq2 = cb[(q0 & 4095) + 2];
    float4 cq3 = cb[(q0 & 4095) + 3];
    float e0 = __builtin_inff(), e1 = __builtin_inff();
    float e2 = __builtin_inff(), e3 = __builtin_inff();

    // Pass A: per-lane cell-min over this wave's 16 candidate rows. ROLLED.
    #pragma unroll 1
    for (int c = 0; c < 16; ++c) {
        float4 cj = cb[(cbase + c) * 64 + lane];
        {
            float dot = __fadd_rn(__fadd_rn(__fmul_rn(cq0.x, cj.x), __fmul_rn(cq0.y, cj.y)),
                                  __fmul_rn(cq0.z, cj.z));
            float d = __fsub_rn(__fadd_rn(cq0.w, cj.w), __fmul_rn(2.0f, dot));
            e0 = fminf(e0, d);
        }
        {
            float dot = __fadd_rn(__fadd_rn(__fmul_rn(cq1.x, cj.x), __fmul_rn(cq1.y, cj.y)),
                                  __fmul_rn(cq1.z, cj.z));
            float d = __fsub_rn(__fadd_rn(cq1.w, cj.w), __fmul_rn(2.0f, dot));
            e1 = fminf(e1, d);
        }
        {
            float dot = __fadd_rn(__fadd_rn(__fmul_rn(cq2.x, cj.x), __fmul_rn(cq2.y, cj.y)),
                                  __fmul_rn(cq2.z, cj.z));
            float d = __fsub_rn(__fadd_rn(cq2.w, cj.w), __fmul_rn(2.0f, dot));
            e2 = fminf(e2, d);
        }
        {
            float dot = __fadd_rn(__fadd_rn(__fmul_rn(cq3.x, cj.x), __fmul_rn(cq3.y, cj.y)),
                                  __fmul_rn(cq3.z, cj.z));
            float d = __fsub_rn(__fadd_rn(cq3.w, cj.w), __fmul_rn(2.0f, dot));
            e3 = fminf(e3, d);
        }
    }
    scratchf[0 * 256 + wv * 64 + lane] = e0;
    scratchf[1 * 256 + wv * 64 + lane] = e1;
    scratchf[2 * 256 + wv * 64 + lane] = e2;
    scratchf[3 * 256 + wv * 64 + lane] = e3;
    __syncthreads();

    // Wave wv: T for query wv = 16th smallest of the 64 combined lane-minima.
    {
        const float* em = scratchf + wv * 256;
        float v = fminf(fminf(em[lane], em[64 + lane]),
                        fminf(em[128 + lane], em[192 + lane]));
        #pragma unroll
        for (int k = 2; k <= 64; k <<= 1) {
            #pragma unroll
            for (int j = k >> 1; j > 0; j >>= 1) {
                float o = __shfl_xor(v, j, 64);
                bool up = ((lane & k) == 0);
                bool lower = ((lane & j) == 0);
                bool takemin = (lower == up);
                bool oless = (o < v);
                v = (takemin == oless) ? o : v;
            }
        }
        float Tq = __shfl(v, 15, 64);
        if (lane == 0) { Tsh[wv] = Tq; cnt[wv] = 0; }
    }
    __syncthreads();

    const float T0 = Tsh[0], T1 = Tsh[1], T2 = Tsh[2], T3 = Tsh[3];

    // Pass B: this wave's 16 rows, all 4 queries; survivors via block atomics.
    // ROLLED.
    #pragma unroll 1
    for (int c = 0; c < 16; ++c) {
        float4 cj = cb[(cbase + c) * 64 + lane];
        unsigned idx = (unsigned)((cbase + c) * 64 + lane);
        {
            float dot = __fadd_rn(__fadd_rn(__fmul_rn(cq0.x, cj.x), __fmul_rn(cq0.y, cj.y)),
                                  __fmul_rn(cq0.z, cj.z));
            float d = __fsub_rn(__fadd_rn(cq0.w, cj.w), __fmul_rn(2.0f, dot));
            if (d <= T0) {
                int pos = atomicAdd(&cnt[0], 1);
                if (pos < 64) {
                    unsigned u = __float_as_uint(d);
                    unsigned ord = (u & 0x80000000u) ? ~u : (u | 0x80000000u);
                    keybuf[0][pos] = ((unsigned long long)ord << 32) | idx;
                }
            }
        }
        {
            float dot = __fadd_rn(__fadd_rn(__fmul_rn(cq1.x, cj.x), __fmul_rn(cq1.y, cj.y)),
                                  __fmul_rn(cq1.z, cj.z));
            float d = __fsub_rn(__fadd_rn(cq1.w, cj.w), __fmul_rn(2.0f, dot));
            if (d <= T1) {
                int pos = atomicAdd(&cnt[1], 1);
                if (pos < 64) {
                    unsigned u = __float_as_uint(d);
                    unsigned ord = (u & 0x80000000u) ? ~u : (u | 0x80000000u);
                    keybuf[1][pos] = ((unsigned long long)ord << 32) | idx;
                }
            }
        }
        {
            float dot = __fadd_rn(__fadd_rn(__fmul_rn(cq2.x, cj.x), __fmul_rn(cq2.y, cj.y)),
                                  __fmul_rn(cq2.z, cj.z));
            float d = __fsub_rn(__fadd_rn(cq2.w, cj.w), __fmul_rn(2.0f, dot));
            if (d <= T2) {
                int pos = atomicAdd(&cnt[2], 1);
                if (pos < 64) {
                    unsigned u = __float_as_uint(d);
                    unsigned ord = (u & 0x80000000u) ? ~u : (u | 0x80000000u);
                    keybuf[2][pos] = ((unsigned long long)ord << 32) | idx;
                }
            }
        }
        {
            float dot = __fadd_rn(__fadd_rn(__fmul_rn(cq3.x, cj.x), __fmul_rn(cq3.y, cj.y)),
                                  __fmul_rn(cq3.z, cj.z));
            float d = __fsub_rn(__fadd_rn(cq3.w, cj.w), __fmul_rn(2.0f, dot));
            if (d <= T3) {
                int pos = atomicAdd(&cnt[3], 1);
                if (pos < 64) {
                    unsigned u = __float_as_uint(d);
                    unsigned ord = (u & 0x80000000u) ? ~u : (u | 0x80000000u);
                    keybuf[3][pos] = ((unsigned long long)ord << 32) | idx;
                }
            }
        }
    }
    __syncthreads();

    // Epilogue: wave wv owns query wv. Reload cqs from global (L2-hot, same
    // address as prologue -> bit-identical) — NO runtime indexing of cq regs.
    const float4 cqs = cb[(q0 & 4095) + wv];
    int cn = cnt[wv];
    if (cn > 64) {
        // Exact fallback (wave-uniform branch; all state per-wave/per-lane,
        // same-wave LDS ordering suffices — NO __syncthreads in here).
        float* lists = scratchf + wv * 1088;   // emin region dead by now
        float dist[16];
        #pragma unroll
        for (int i = 0; i < 16; ++i) dist[i] = __builtin_inff();
        #pragma unroll 1
        for (int c = 0; c < 64; ++c) {
            float4 cj = cb[c * 64 + lane];
            float dot = __fadd_rn(__fadd_rn(__fmul_rn(cqs.x, cj.x), __fmul_rn(cqs.y, cj.y)),
                                  __fmul_rn(cqs.z, cj.z));
            float d = __fsub_rn(__fadd_rn(cqs.w, cj.w), __fmul_rn(2.0f, dot));
            #pragma unroll
            for (int i = 15; i > 0; --i)
                dist[i] = __builtin_amdgcn_fmed3f(dist[i - 1], d, dist[i]);
            dist[0] = fminf(dist[0], d);
        }
        #pragma unroll
        for (int i = 0; i < 16; ++i) lists[lane * 17 + i] = dist[i];

        float h2 = dist[0];
        int p2 = 0;
        float d16 = 0.0f;
        for (int it = 0; it < 16; ++it) {
            float m = h2;
            #pragma unroll
            for (int off = 32; off > 0; off >>= 1) m = fminf(m, __shfl_xor(m, off, 64));
            unsigned long long msk = __ballot(h2 == m);
            int first = __ffsll((unsigned long long)msk) - 1;
            if (lane == first) {
                p2++;
                h2 = (p2 < 16) ? lists[lane * 17 + p2] : __builtin_inff();
            }
            d16 = m;
        }

        if (lane == 0) cnt[wv] = 0;   // same-wave ds ordering: reset precedes atomics
        #pragma unroll 1
        for (int c = 0; c < 64; ++c) {
            float4 cj = cb[c * 64 + lane];
            float dot = __fadd_rn(__fadd_rn(__fmul_rn(cqs.x, cj.x), __fmul_rn(cqs.y, cj.y)),
                                  __fmul_rn(cqs.z, cj.z));
            float d = __fsub_rn(__fadd_rn(cqs.w, cj.w), __fmul_rn(2.0f, dot));
            if (d <= d16) {
                int pos = atomicAdd(&cnt[wv], 1);
                if (pos < 64) {
                    unsigned u = __float_as_uint(d);
                    unsigned ord = (u & 0x80000000u) ? ~u : (u | 0x80000000u);
                    keybuf[wv][pos] =
                        ((unsigned long long)ord << 32) | (unsigned)(c * 64 + lane);
                }
            }
        }
        cn = cnt[wv];
    }

    int mcount = cn < 64 ? cn : 64;
    unsigned long long key = (lane < mcount) ? keybuf[wv][lane] : ~0ull;
    // 64-lane bitonic sort ascending on (d, idx).
    #pragma unroll
    for (int k = 2; k <= 64; k <<= 1) {
        #pragma unroll
        for (int j = k >> 1; j > 0; j >>= 1) {
            unsigned long long o = __shfl_xor(key, j, 64);
            bool up = ((lane & k) == 0);
            bool lower = ((lane & j) == 0);
            bool takemin = (lower == up);
            bool oless = (o < key);
            key = (takemin == oless) ? o : key;
        }
    }
    if (lane < 16) knn[(q0 + wv) * 16 + lane] = (int)(unsigned)(key & 0xffffffffull);
}

// ---------------------------------------------------------------------------
// Kernel C: fused attention. R14-verbatim (proven) except the W2 epilogue
// uses 4 independent partial accumulators (16-deep FMA chains + tree sum)
// instead of one 64-deep dependent chain. Pure f32 reassociation; ~1 ulp
// change in out0, far inside threshold.
// ---------------------------------------------------------------------------
__global__ __launch_bounds__(256, 4) void attn_kernel(
    const u16* __restrict__ qb, const u16* __restrict__ kb, const u16* __restrict__ vb,
    const float4* __restrict__ c4, const int* __restrict__ knn,
    const u16* __restrict__ wfrag,
    const float* __restrict__ Wp1, const float* __restrict__ bp1, const float* __restrict__ bp2,
    const float* __restrict__ bm1, const float* __restrict__ bm2,
    const float* __restrict__ b2,
    const float* __restrict__ feats,
    float* __restrict__ out0, float* __restrict__ out_att)
{
    // union region per (wv,it): [0..576) floats = pgbuf (16*72 u16 = 2304B);
    // then att staging 1024 floats; then obuf 64 floats. Phases are ordered
    // within the owning wave -> no barriers needed.
    __shared__ __align__(16) float smem[4][2][1024];
    __shared__ float relbuf[4][2][16][4];
    __shared__ int   idxbuf[4][2][16];

    const int tid = threadIdx.x;
    const int lane = tid & 63, wv = tid >> 6;
    const int qbase = blockIdx.x * 8 + wv * 2;   // this wave's 2 queries
    const int bb = qbase >> 12;                  // 8 | 4096 -> same batch
    const int col = lane & 15, quad = lane >> 4;
    const int m = col;                           // neighbor row for A-operand

    if (lane < 16) {
        #pragma unroll
        for (int it = 0; it < 2; ++it) {
            int q = qbase + it;
            int jj = knn[q * 16 + lane] & 4095;
            idxbuf[wv][it][lane] = jj;
            float4 cj = c4[(bb << 12) + jj];
            float4 cn = c4[q];
            relbuf[wv][it][lane][0] = cn.x - cj.x;
            relbuf[wv][it][lane][1] = cn.y - cj.y;
            relbuf[wv][it][lane][2] = cn.z - cj.z;
        }
    }
    // same-wave LDS handoff: no barrier needed.

    // V prefetch (early, latency hides under t/pos phases). Static idx only.
    float vpre[2][4][4];   // [it][r][nt]
    #pragma unroll
    for (int it = 0; it < 2; ++it)
        #pragma unroll
        for (int r = 0; r < 4; ++r) {
            int jr = idxbuf[wv][it][quad * 4 + r];
            const u16* vp = vb + (size_t)((bb << 12) + jr) * 64;
            #pragma unroll
            for (int nt = 0; nt < 4; ++nt)
                vpre[it][r][nt] = b2f(vp[nt * 16 + col]);
        }

    float rr[2][3];
    #pragma unroll
    for (int it = 0; it < 2; ++it) {
        rr[it][0] = relbuf[wv][it][m][0];
        rr[it][1] = relbuf[wv][it][m][1];
        rr[it][2] = relbuf[wv][it][m][2];
    }

    // t = relu(rel @ Wp1 + bp1), A-fragment layout, both queries (Wp1 shared).
    v8s a0[2], a1[2];
    #pragma unroll
    for (int hh = 0; hh < 2; ++hh) {
        int tb = hh * 32 + quad * 8;
        #pragma unroll
        for (int j = 0; j < 8; ++j) {
            float w0 = Wp1[0 * 64 + tb + j];
            float w1 = Wp1[1 * 64 + tb + j];
            float w2 = Wp1[2 * 64 + tb + j];
            float bp = bp1[tb + j];
            #pragma unroll
            for (int it = 0; it < 2; ++it) {
                float t = bp;
                t = fmaf(rr[it][0], w0, t);
                t = fmaf(rr[it][1], w1, t);
                t = fmaf(rr[it][2], w2, t);
                t = fmaxf(t, 0.0f);
                if (hh == 0) a0[it][j] = (short)f2b(t); else a1[it][j] = (short)f2b(t);
            }
        }
    }

    // pos = t @ Wp2 + bp2 (C-layout), both queries; vw = v + pos folded here.
    float vw[2][4][4];   // [it][r][nt]; the only long-lived state after this.
    #pragma unroll
    for (int nt = 0; nt < 4; ++nt) {
        float bias = bp2[nt * 16 + col];
        v8s bf0 = *(const v8s*)(wfrag + (0 + nt) * 512 + lane * 8);
        v8s bf1 = *(const v8s*)(wfrag + (4 + nt) * 512 + lane * 8);
        #pragma unroll
        for (int it = 0; it < 2; ++it) {
            v4f acc = {bias, bias, bias, bias};
            acc = __builtin_amdgcn_mfma_f32_16x16x32_bf16(a0[it], bf0, acc, 0, 0, 0);
            acc = __builtin_amdgcn_mfma_f32_16x16x32_bf16(a1[it], bf1, acc, 0, 0, 0);
            u16* pg = (u16*)&smem[wv][it][0];
            #pragma unroll
            for (int r = 0; r < 4; ++r) {
                pg[(quad * 4 + r) * 72 + nt * 16 + col] = f2b(acc[r]);
                vw[it][r][nt] = vpre[it][r][nt] + acc[r];
            }
        }
    }

    // h = q - k + pos in A-layout (bf16 inputs), both queries.
    v8s ha0[2], ha1[2];
    #pragma unroll
    for (int it = 0; it < 2; ++it) {
        int q = qbase + it;
        int jm = idxbuf[wv][it][m];
        const u16* qp = qb + (size_t)q * 64;
        const u16* kp = kb + (size_t)((bb << 12) + jm) * 64;
        const u16* pg = (const u16*)&smem[wv][it][0];
        #pragma unroll
        for (int hh = 0; hh < 2; ++hh) {
            int tb = hh * 32 + quad * 8;
            v8u qv = *(const v8u*)(qp + tb);
            v8u kv = *(const v8u*)(kp + tb);
            v8u pv = *(const v8u*)(pg + m * 72 + tb);
            #pragma unroll
            for (int j = 0; j < 8; ++j) {
                float hv = b2f(qv[j]) - b2f(kv[j]) + b2f(pv[j]);
                if (hh == 0) ha0[it][j] = (short)f2b(hv); else ha1[it][j] = (short)f2b(hv);
            }
        }
    }

    // g = relu(h @ Wm1 + bm1) -> pgbuf (bf16, C-layout scatter).
    // WAR on pgbuf vs pv reads above: same-wave program order -> safe.
    #pragma unroll
    for (int nt = 0; nt < 4; ++nt) {
        float bias = bm1[nt * 16 + col];
        v8s bf0 = *(const v8s*)(wfrag + 4096 + (0 + nt) * 512 + lane * 8);
        v8s bf1 = *(const v8s*)(wfrag + 4096 + (4 + nt) * 512 + lane * 8);
        #pragma unroll
        for (int it = 0; it < 2; ++it) {
            v4f acc = {bias, bias, bias, bias};
            acc = __builtin_amdgcn_mfma_f32_16x16x32_bf16(ha0[it], bf0, acc, 0, 0, 0);
            acc = __builtin_amdgcn_mfma_f32_16x16x32_bf16(ha1[it], bf1, acc, 0, 0, 0);
            u16* pg = (u16*)&smem[wv][it][0];
            #pragma unroll
            for (int r = 0; r < 4; ++r)
                pg[(quad * 4 + r) * 72 + nt * 16 + col] = f2b(fmaxf(acc[r], 0.0f));
        }
    }

    // ga fragments (bf16 vectors), both queries. pgbuf dead after this.
    v8s ga0[2], ga1[2];
    #pragma unroll
    for (int it = 0; it < 2; ++it) {
        const u16* pg = (const u16*)&smem[wv][it][0];
        ga0[it] = *(const v8s*)(pg + m * 72 + quad * 8);
        ga1[it] = *(const v8s*)(pg + m * 72 + 32 + quad * 8);
    }

    // att = g @ Wm2 + bm2, fused softmax; att values staged in LDS (f32)
    // over the dead pgbuf region for coalesced global write.
    float o4[2][4];
    #pragma unroll
    for (int nt = 0; nt < 4; ++nt) {
        float bias = bm2[nt * 16 + col];
        v8s bf0 = *(const v8s*)(wfrag + 8192 + (0 + nt) * 512 + lane * 8);
        v8s bf1 = *(const v8s*)(wfrag + 8192 + (4 + nt) * 512 + lane * 8);
        #pragma unroll
        for (int it = 0; it < 2; ++it) {
            v4f acc = {bias, bias, bias, bias};
            acc = __builtin_amdgcn_mfma_f32_16x16x32_bf16(ga0[it], bf0, acc, 0, 0, 0);
            acc = __builtin_amdgcn_mfma_f32_16x16x32_bf16(ga1[it], bf1, acc, 0, 0, 0);

            float s[4];
            #pragma unroll
            for (int r = 0; r < 4; ++r) s[r] = acc[r] * 0.125f;
            float mx = fmaxf(fmaxf(s[0], s[1]), fmaxf(s[2], s[3]));
            mx = fmaxf(mx, __shfl_xor(mx, 16, 64));
            mx = fmaxf(mx, __shfl_xor(mx, 32, 64));
            float e[4], sum = 0.0f;
            #pragma unroll
            for (int r = 0; r < 4; ++r) { e[r] = __expf(s[r] - mx); sum += e[r]; }
            sum += __shfl_xor(sum, 16, 64);
            sum += __shfl_xor(sum, 32, 64);
            float inv = 1.0f / sum;

            float o = 0.0f;
            #pragma unroll
            for (int r = 0; r < 4; ++r) {
                float a = e[r] * inv;
                smem[wv][it][(quad * 4 + r) * 64 + nt * 16 + col] = a;
                o = fmaf(a, vw[it][r][nt], o);
            }
            o += __shfl_xor(o, 16, 64);
            o += __shfl_xor(o, 32, 64);
            o4[it][nt] = o;
        }
    }
    // same-wave LDS handoff: all att ds_writes precede the reads below.

    // out_att: coalesced float4 stores, 1KB/instruction, each line once.
    #pragma unroll
    for (int it = 0; it < 2; ++it) {
        float* dst = out_att + (size_t)(qbase + it) * 1024;
        #pragma unroll
        for (int chunk = 0; chunk < 4; ++chunk) {
            float4 v4 = *(const float4*)&smem[wv][it][chunk * 256 + lane * 4];
            *(float4*)&dst[chunk * 256 + lane * 4] = v4;
        }
    }

    // obuf alias over dead att staging (reads above already in registers).
    #pragma unroll
    for (int it = 0; it < 2; ++it) {
        if (quad == 0) {
            #pragma unroll
            for (int nt = 0; nt < 4; ++nt) smem[wv][it][nt * 16 + col] = o4[it][nt];
        }
    }
    // same-wave LDS handoff: no barrier needed.

    // out = o @ W2 + b2 + features   (W2bt: bf16, transposed, L1/L2-hot);
    // w8 loaded once, shared by both queries. 4 partial accumulators break
    // the 64-deep dependent FMA chain (R17).
    const u16* wrow = wfrag + 3 * 4096 + lane * 64;
    v8u w8[8];
    #pragma unroll
    for (int c = 0; c < 8; ++c) w8[c] = *(const v8u*)(wrow + c * 8);
    #pragma unroll
    for (int it = 0; it < 2; ++it) {
        int q = qbase + it;
        const float* ob = &smem[wv][it][0];
        float p0 = 0.0f, p1 = 0.0f, p2 = 0.0f, p3 = 0.0f;
        #pragma unroll
        for (int g4 = 0; g4 < 4; ++g4) {
            #pragma unroll
            for (int cc = 0; cc < 4; ++cc) {
                int c = g4 * 4 + cc;
                float4 ov = *(const float4*)&ob[c * 4];
                float pp = (g4 == 0) ? p0 : (g4 == 1) ? p1 : (g4 == 2) ? p2 : p3;
                pp = fmaf(ov.x, b2f(w8[c >> 1][(c & 1) * 4 + 0]), pp);
                pp = fmaf(ov.y, b2f(w8[c >> 1][(c & 1) * 4 + 1]), pp);
                pp = fmaf(ov.z, b2f(w8[c >> 1][(c & 1) * 4 + 2]), pp);
                pp = fmaf(ov.w, b2f(w8[c >> 1][(c & 1) * 4 + 3]), pp);
                if (g4 == 0) p0 = pp; else if (g4 == 1) p1 = pp;
                else if (g4 == 2) p2 = pp; else p3 = pp;
            }
        }
        float base = b2[lane] + feats[(size_t)q * 64 + lane];
        out0[(size_t)q * 64 + lane] = base + ((p0 + p1) + (p2 + p3));
    }
}

// ---------------------------------------------------------------------------
extern "C" void kernel_launch(void* const* d_in, const int* in_sizes, int n_in,
                              void* d_out, int out_size, void* d_ws, size_t ws_size,
                              hipStream_t stream)
{
    (void)in_sizes; (void)n_in; (void)out_size; (void)ws_size;
    const float* coords = (const float*)d_in[0];
    const float* feats  = (const float*)d_in[1];
    const float* W1  = (const float*)d_in[2];
    const float* b1  = (const float*)d_in[3];
    const float* Wq  = (const float*)d_in[4];
    const float* Wk  = (const float*)d_in[5];
    const float* Wv  = (const float*)d_in[6];
    const float* Wm1 = (const float*)d_in[7];
    const float* bm1 = (const float*)d_in[8];
    const float* Wm2 = (const float*)d_in[9];
    const float* bm2 = (const float*)d_in[10];
    const float* Wp1 = (const float*)d_in[11];
    const float* bp1 = (const float*)d_in[12];
    const float* Wp2 = (const float*)d_in[13];
    const float* bp2 = (const float*)d_in[14];
    const float* W2  = (const float*)d_in[15];
    const float* b2  = (const float*)d_in[16];

    char* ws = (char*)d_ws;
    u16*    qb    = (u16*)(ws);
    u16*    kb    = (u16*)(ws + (4u << 20));
    u16*    vb    = (u16*)(ws + (8u << 20));
    float4* c4    = (float4*)(ws + (12u << 20));
    int*    knn   = (int*)(ws + (12u << 20) + (256u << 10));
    u16*    wfrag = (u16*)(ws + (12u << 20) + (256u << 10) + (1u << 20));

    float* out0    = (float*)d_out;
    float* out_att = out0 + (size_t)4 * 4096 * 64;

    prep_kernel<<<260, 256, 0, stream>>>(feats, coords, W1, b1, Wq, Wk, Wv,
                                         Wp2, Wm1, Wm2, W2,
                                         qb, kb, vb, c4, wfrag);
    knn_kernel<<<4096, 256, 0, stream>>>(c4, knn);
    attn_kernel<<<2048, 256, 0, stream>>>(qb, kb, vb, c4, knn, wfrag,
                                          Wp1, bp1, bp2, bm1, bm2, b2, feats,
                                          out0, out_att);
}

// Round 12
// 191.839 us; speedup vs baseline: 1.1104x; 1.0090x over previous
//
#include <hip/hip_runtime.h>
#include <cstdint>

typedef unsigned short u16;
typedef short v8s __attribute__((ext_vector_type(8)));
typedef u16   v8u __attribute__((ext_vector_type(8)));
typedef float v4f __attribute__((ext_vector_type(4)));

static __device__ __forceinline__ u16 f2b(float f) {
    unsigned u = __float_as_uint(f);
    unsigned r = (u + 0x7fffu + ((u >> 16) & 1u)) >> 16;
    return (u16)r;
}
static __device__ __forceinline__ float b2f(u16 u) {
    return __uint_as_float(((unsigned)u) << 16);
}

// QUARANTINE NOTE (R3/R4, reconfirmed R9): unrolled knn candidate loops ->
// deterministic wrong result. ALL candidate (c) loops carry an explicit
// `#pragma unroll 1`. No candidate register arrays.
// QUARANTINE NOTE 2 (R18): packed f32x2 distance math -> wrong result
// (absmax 0.171; fp contract pragma didn't govern ext-vector ops -> pk_fma
// fused, different rounding). knn per-pair arithmetic stays VERBATIM SCALAR
// __f*_rn — no packing, no reassociation, ever.
// RULE-20 NOTE (R10): runtime-indexed register arrays -> scratch -> huge HBM
// traffic. All register arrays use compile-time indices only.
// WRITE-AMP NOTE (R13): scattered 4B stores -> partial-line write amp.
// out_att staged in LDS, written float4-coalesced.
// FUSION NOTE (R15/R16): fusing knn+attn REGRESSED (occupancy clash).
// R19 = R17 verbatim (proven best, 193.6 us).

// ---------------------------------------------------------------------------
// Kernel A (fused): blocks 0..255: x = feats@W1+b1; q/k/v = x@W{q,k,v} (bf16);
// c4=[x,y,z,sq]. Blocks 256..258: Wp2/Wm1/Wm2 -> MFMA B-fragment order.
// Block 259: W2 transposed bf16.
// ---------------------------------------------------------------------------
__global__ __launch_bounds__(256) void prep_kernel(
    const float* __restrict__ feats, const float* __restrict__ coords,
    const float* __restrict__ W1, const float* __restrict__ b1,
    const float* __restrict__ Wq, const float* __restrict__ Wk, const float* __restrict__ Wv,
    const float* __restrict__ Wp2, const float* __restrict__ Wm1,
    const float* __restrict__ Wm2, const float* __restrict__ W2,
    u16* __restrict__ qb, u16* __restrict__ kb, u16* __restrict__ vb,
    float4* __restrict__ c4, u16* __restrict__ wfrag)
{
    const int tid = threadIdx.x;
    if (blockIdx.x >= 256) {
        int wb = blockIdx.x - 256;
        if (wb == 3) {
            for (int i = 0; i < 16; ++i) {
                int d = i * 256 + tid;       // d = l*64 + t
                int l = d >> 6, t = d & 63;
                wfrag[3 * 4096 + d] = f2b(W2[t * 64 + l]);
            }
        } else {
            const float* srcs[3] = {Wp2, Wm1, Wm2};
            const float* W = srcs[wb];
            for (int i = 0; i < 16; ++i) {
                int d = i * 256 + tid;      // 0..4095
                int f = d >> 9;
                int lane = (d >> 3) & 63;
                int j = d & 7;
                int k = (f >> 2) * 32 + (lane >> 4) * 8 + j;
                int n = (f & 3) * 16 + (lane & 15);
                wfrag[wb * 4096 + d] = f2b(W[k * 64 + n]);
            }
        }
        return;
    }

    __shared__ float sA[64 * 64];
    __shared__ float wB[64 * 64];
    __shared__ float xt[64 * 64];
    const int gp0 = blockIdx.x * 64;

    if (tid < 64) {
        int p = gp0 + tid;
        float x = coords[p * 3 + 0];
        float y = coords[p * 3 + 1];
        float z = coords[p * 3 + 2];
        float sq = __fadd_rn(__fadd_rn(__fmul_rn(x, x), __fmul_rn(y, y)), __fmul_rn(z, z));
        c4[p] = make_float4(x, y, z, sq);
    }

    #pragma unroll
    for (int i = 0; i < 4; ++i) {
        int chunk = i * 256 + tid;          // 1024 chunks of 4 floats
        ((float4*)sA)[chunk] = ((const float4*)(feats + (size_t)gp0 * 64))[chunk];
        ((float4*)wB)[chunk] = ((const float4*)W1)[chunk];
    }
    __syncthreads();

    const int tx = tid & 15, py = tid >> 4;
    const int c0 = tx * 4, p0 = py * 4;

    {
        float acc[4][4] = {};
        for (int k = 0; k < 64; ++k) {
            float a_[4], w_[4];
            #pragma unroll
            for (int i = 0; i < 4; ++i) a_[i] = sA[(p0 + i) * 64 + k];
            #pragma unroll
            for (int j = 0; j < 4; ++j) w_[j] = wB[k * 64 + c0 + j];
            #pragma unroll
            for (int i = 0; i < 4; ++i)
                #pragma unroll
                for (int j = 0; j < 4; ++j)
                    acc[i][j] = fmaf(a_[i], w_[j], acc[i][j]);
        }
        float bs[4];
        #pragma unroll
        for (int j = 0; j < 4; ++j) bs[j] = b1[c0 + j];
        #pragma unroll
        for (int i = 0; i < 4; ++i)
            #pragma unroll
            for (int j = 0; j < 4; ++j)
                xt[(p0 + i) * 64 + c0 + j] = acc[i][j] + bs[j];
    }
    __syncthreads();

    const float* Ws[3] = {Wq, Wk, Wv};
    u16* Os[3] = {qb, kb, vb};
    for (int mtx = 0; mtx < 3; ++mtx) {
        #pragma unroll
        for (int i = 0; i < 4; ++i) {
            int chunk = i * 256 + tid;
            ((float4*)wB)[chunk] = ((const float4*)Ws[mtx])[chunk];
        }
        __syncthreads();
        float acc[4][4] = {};
        for (int k = 0; k < 64; ++k) {
            float a_[4], w_[4];
            #pragma unroll
            for (int i = 0; i < 4; ++i) a_[i] = xt[(p0 + i) * 64 + k];
            #pragma unroll
            for (int j = 0; j < 4; ++j) w_[j] = wB[k * 64 + c0 + j];
            #pragma unroll
            for (int i = 0; i < 4; ++i)
                #pragma unroll
                for (int j = 0; j < 4; ++j)
                    acc[i][j] = fmaf(a_[i], w_[j], acc[i][j]);
        }
        #pragma unroll
        for (int i = 0; i < 4; ++i) {
            ushort4 st;
            st.x = f2b(acc[i][0]); st.y = f2b(acc[i][1]);
            st.z = f2b(acc[i][2]); st.w = f2b(acc[i][3]);
            *(ushort4*)(Os[mtx] + (size_t)(gp0 + p0 + i) * 64 + c0) = st;
        }
        __syncthreads();
    }
}

// ---------------------------------------------------------------------------
// Kernel B: exact KNN — R11-verbatim (hardware-proven).
// ---------------------------------------------------------------------------
__global__ __launch_bounds__(256) void knn_kernel(
    const float4* __restrict__ c4, int* __restrict__ knn)
{
    // scratchf overlay:
    //   phase A/T: emin[s][w*64+lane] = first 1024 floats (s*256 + w*64 + lane)
    //   fallback : per-wave lists, wave wv uses scratchf + wv*1088 (17*64)
    __shared__ float scratchf[4 * 17 * 64];
    __shared__ unsigned long long keybuf[4][64];
    __shared__ int cnt[4];
    __shared__ float Tsh[4];

    const int tid = threadIdx.x;
    const int lane = tid & 63, wv = tid >> 6;
    const int q0 = blockIdx.x * 4;                 // this block's 4 queries
    const int b = q0 >> 12;                        // 4 | 4096 -> same batch
    const float4* cb = c4 + ((size_t)b << 12);
    const int cbase = wv * 16;                     // this wave's candidate rows

    float4 cq0 = cb[(q0 & 4095) + 0];
    float4 cq1 = cb[(q0 & 4095) + 1];
    float4 cq2 = cb[(q0 & 4095) + 2];
    float4 cq3 = cb[(q0 & 4095) + 3];
    float e0 = __builtin_inff(), e1 = __builtin_inff();
    float e2 = __builtin_inff(), e3 = __builtin_inff();

    // Pass A: per-lane cell-min over this wave's 16 candidate rows. ROLLED.
    #pragma unroll 1
    for (int c = 0; c < 16; ++c) {
        float4 cj = cb[(cbase + c) * 64 + lane];
        {
            float dot = __fadd_rn(__fadd_rn(__fmul_rn(cq0.x, cj.x), __fmul_rn(cq0.y, cj.y)),
                                  __fmul_rn(cq0.z, cj.z));
            float d = __fsub_rn(__fadd_rn(cq0.w, cj.w), __fmul_rn(2.0f, dot));
            e0 = fminf(e0, d);
        }
        {
            float dot = __fadd_rn(__fadd_rn(__fmul_rn(cq1.x, cj.x), __fmul_rn(cq1.y, cj.y)),
                                  __fmul_rn(cq1.z, cj.z));
            float d = __fsub_rn(__fadd_rn(cq1.w, cj.w), __fmul_rn(2.0f, dot));
            e1 = fminf(e1, d);
        }
        {
            float dot = __fadd_rn(__fadd_rn(__fmul_rn(cq2.x, cj.x), __fmul_rn(cq2.y, cj.y)),
                                  __fmul_rn(cq2.z, cj.z));
            float d = __fsub_rn(__fadd_rn(cq2.w, cj.w), __fmul_rn(2.0f, dot));
            e2 = fminf(e2, d);
        }
        {
            float dot = __fadd_rn(__fadd_rn(__fmul_rn(cq3.x, cj.x), __fmul_rn(cq3.y, cj.y)),
                                  __fmul_rn(cq3.z, cj.z));
            float d = __fsub_rn(__fadd_rn(cq3.w, cj.w), __fmul_rn(2.0f, dot));
            e3 = fminf(e3, d);
        }
    }
    scratchf[0 * 256 + wv * 64 + lane] = e0;
    scratchf[1 * 256 + wv * 64 + lane] = e1;
    scratchf[2 * 256 + wv * 64 + lane] = e2;
    scratchf[3 * 256 + wv * 64 + lane] = e3;
    __syncthreads();

    // Wave wv: T for query wv = 16th smallest of the 64 combined lane-minima.
    {
        const float* em = scratchf + wv * 256;
        float v = fminf(fminf(em[lane], em[64 + lane]),
                        fminf(em[128 + lane], em[192 + lane]));
        #pragma unroll
        for (int k = 2; k <= 64; k <<= 1) {
            #pragma unroll
            for (int j = k >> 1; j > 0; j >>= 1) {
                float o = __shfl_xor(v, j, 64);
                bool up = ((lane & k) == 0);
                bool lower = ((lane & j) == 0);
                bool takemin = (lower == up);
                bool oless = (o < v);
                v = (takemin == oless) ? o : v;
            }
        }
        float Tq = __shfl(v, 15, 64);
        if (lane == 0) { Tsh[wv] = Tq; cnt[wv] = 0; }
    }
    __syncthreads();

    const float T0 = Tsh[0], T1 = Tsh[1], T2 = Tsh[2], T3 = Tsh[3];

    // Pass B: this wave's 16 rows, all 4 queries; survivors via block atomics.
    // ROLLED.
    #pragma unroll 1
    for (int c = 0; c < 16; ++c) {
        float4 cj = cb[(cbase + c) * 64 + lane];
        unsigned idx = (unsigned)((cbase + c) * 64 + lane);
        {
            float dot = __fadd_rn(__fadd_rn(__fmul_rn(cq0.x, cj.x), __fmul_rn(cq0.y, cj.y)),
                                  __fmul_rn(cq0.z, cj.z));
            float d = __fsub_rn(__fadd_rn(cq0.w, cj.w), __fmul_rn(2.0f, dot));
            if (d <= T0) {
                int pos = atomicAdd(&cnt[0], 1);
                if (pos < 64) {
                    unsigned u = __float_as_uint(d);
                    unsigned ord = (u & 0x80000000u) ? ~u : (u | 0x80000000u);
                    keybuf[0][pos] = ((unsigned long long)ord << 32) | idx;
                }
            }
        }
        {
            float dot = __fadd_rn(__fadd_rn(__fmul_rn(cq1.x, cj.x), __fmul_rn(cq1.y, cj.y)),
                                  __fmul_rn(cq1.z, cj.z));
            float d = __fsub_rn(__fadd_rn(cq1.w, cj.w), __fmul_rn(2.0f, dot));
            if (d <= T1) {
                int pos = atomicAdd(&cnt[1], 1);
                if (pos < 64) {
                    unsigned u = __float_as_uint(d);
                    unsigned ord = (u & 0x80000000u) ? ~u : (u | 0x80000000u);
                    keybuf[1][pos] = ((unsigned long long)ord << 32) | idx;
                }
            }
        }
        {
            float dot = __fadd_rn(__fadd_rn(__fmul_rn(cq2.x, cj.x), __fmul_rn(cq2.y, cj.y)),
                                  __fmul_rn(cq2.z, cj.z));
            float d = __fsub_rn(__fadd_rn(cq2.w, cj.w), __fmul_rn(2.0f, dot));
            if (d <= T2) {
                int pos = atomicAdd(&cnt[2], 1);
                if (pos < 64) {
                    unsigned u = __float_as_uint(d);
                    unsigned ord = (u & 0x80000000u) ? ~u : (u | 0x80000000u);
                    keybuf[2][pos] = ((unsigned long long)ord << 32) | idx;
                }
            }
        }
        {
            float dot = __fadd_rn(__fadd_rn(__fmul_rn(cq3.x, cj.x), __fmul_rn(cq3.y, cj.y)),
                                  __fmul_rn(cq3.z, cj.z));
            float d = __fsub_rn(__fadd_rn(cq3.w, cj.w), __fmul_rn(2.0f, dot));
            if (d <= T3) {
                int pos = atomicAdd(&cnt[3], 1);
                if (pos < 64) {
                    unsigned u = __float_as_uint(d);
                    unsigned ord = (u & 0x80000000u) ? ~u : (u | 0x80000000u);
                    keybuf[3][pos] = ((unsigned long long)ord << 32) | idx;
                }
            }
        }
    }
    __syncthreads();

    // Epilogue: wave wv owns query wv. Reload cqs from global (L2-hot, same
    // address as prologue -> bit-identical) — NO runtime indexing of cq regs.
    const float4 cqs = cb[(q0 & 4095) + wv];
    int cn = cnt[wv];
    if (cn > 64) {
        // Exact fallback (wave-uniform branch; all state per-wave/per-lane,
        // same-wave LDS ordering suffices — NO __syncthreads in here).
        float* lists = scratchf + wv * 1088;   // emin region dead by now
        float dist[16];
        #pragma unroll
        for (int i = 0; i < 16; ++i) dist[i] = __builtin_inff();
        #pragma unroll 1
        for (int c = 0; c < 64; ++c) {
            float4 cj = cb[c * 64 + lane];
            float dot = __fadd_rn(__fadd_rn(__fmul_rn(cqs.x, cj.x), __fmul_rn(cqs.y, cj.y)),
                                  __fmul_rn(cqs.z, cj.z));
            float d = __fsub_rn(__fadd_rn(cqs.w, cj.w), __fmul_rn(2.0f, dot));
            #pragma unroll
            for (int i = 15; i > 0; --i)
                dist[i] = __builtin_amdgcn_fmed3f(dist[i - 1], d, dist[i]);
            dist[0] = fminf(dist[0], d);
        }
        #pragma unroll
        for (int i = 0; i < 16; ++i) lists[lane * 17 + i] = dist[i];

        float h2 = dist[0];
        int p2 = 0;
        float d16 = 0.0f;
        for (int it = 0; it < 16; ++it) {
            float m = h2;
            #pragma unroll
            for (int off = 32; off > 0; off >>= 1) m = fminf(m, __shfl_xor(m, off, 64));
            unsigned long long msk = __ballot(h2 == m);
            int first = __ffsll((unsigned long long)msk) - 1;
            if (lane == first) {
                p2++;
                h2 = (p2 < 16) ? lists[lane * 17 + p2] : __builtin_inff();
            }
            d16 = m;
        }

        if (lane == 0) cnt[wv] = 0;   // same-wave ds ordering: reset precedes atomics
        #pragma unroll 1
        for (int c = 0; c < 64; ++c) {
            float4 cj = cb[c * 64 + lane];
            float dot = __fadd_rn(__fadd_rn(__fmul_rn(cqs.x, cj.x), __fmul_rn(cqs.y, cj.y)),
                                  __fmul_rn(cqs.z, cj.z));
            float d = __fsub_rn(__fadd_rn(cqs.w, cj.w), __fmul_rn(2.0f, dot));
            if (d <= d16) {
                int pos = atomicAdd(&cnt[wv], 1);
                if (pos < 64) {
                    unsigned u = __float_as_uint(d);
                    unsigned ord = (u & 0x80000000u) ? ~u : (u | 0x80000000u);
                    keybuf[wv][pos] =
                        ((unsigned long long)ord << 32) | (unsigned)(c * 64 + lane);
                }
            }
        }
        cn = cnt[wv];
    }

    int mcount = cn < 64 ? cn : 64;
    unsigned long long key = (lane < mcount) ? keybuf[wv][lane] : ~0ull;
    // 64-lane bitonic sort ascending on (d, idx).
    #pragma unroll
    for (int k = 2; k <= 64; k <<= 1) {
        #pragma unroll
        for (int j = k >> 1; j > 0; j >>= 1) {
            unsigned long long o = __shfl_xor(key, j, 64);
            bool up = ((lane & k) == 0);
            bool lower = ((lane & j) == 0);
            bool takemin = (lower == up);
            bool oless = (o < key);
            key = (takemin == oless) ? o : key;
        }
    }
    if (lane < 16) knn[(q0 + wv) * 16 + lane] = (int)(unsigned)(key & 0xffffffffull);
}

// ---------------------------------------------------------------------------
// Kernel C: fused attention. R14-verbatim (proven) except the W2 epilogue
// uses 4 independent partial accumulators (16-deep FMA chains + tree sum)
// instead of one 64-deep dependent chain. Pure f32 reassociation; ~1 ulp
// change in out0, far inside threshold.
// ---------------------------------------------------------------------------
__global__ __launch_bounds__(256, 4) void attn_kernel(
    const u16* __restrict__ qb, const u16* __restrict__ kb, const u16* __restrict__ vb,
    const float4* __restrict__ c4, const int* __restrict__ knn,
    const u16* __restrict__ wfrag,
    const float* __restrict__ Wp1, const float* __restrict__ bp1, const float* __restrict__ bp2,
    const float* __restrict__ bm1, const float* __restrict__ bm2,
    const float* __restrict__ b2,
    const float* __restrict__ feats,
    float* __restrict__ out0, float* __restrict__ out_att)
{
    // union region per (wv,it): [0..576) floats = pgbuf (16*72 u16 = 2304B);
    // then att staging 1024 floats; then obuf 64 floats. Phases are ordered
    // within the owning wave -> no barriers needed.
    __shared__ __align__(16) float smem[4][2][1024];
    __shared__ float relbuf[4][2][16][4];
    __shared__ int   idxbuf[4][2][16];

    const int tid = threadIdx.x;
    const int lane = tid & 63, wv = tid >> 6;
    const int qbase = blockIdx.x * 8 + wv * 2;   // this wave's 2 queries
    const int bb = qbase >> 12;                  // 8 | 4096 -> same batch
    const int col = lane & 15, quad = lane >> 4;
    const int m = col;                           // neighbor row for A-operand

    if (lane < 16) {
        #pragma unroll
        for (int it = 0; it < 2; ++it) {
            int q = qbase + it;
            int jj = knn[q * 16 + lane] & 4095;
            idxbuf[wv][it][lane] = jj;
            float4 cj = c4[(bb << 12) + jj];
            float4 cn = c4[q];
            relbuf[wv][it][lane][0] = cn.x - cj.x;
            relbuf[wv][it][lane][1] = cn.y - cj.y;
            relbuf[wv][it][lane][2] = cn.z - cj.z;
        }
    }
    // same-wave LDS handoff: no barrier needed.

    // V prefetch (early, latency hides under t/pos phases). Static idx only.
    float vpre[2][4][4];   // [it][r][nt]
    #pragma unroll
    for (int it = 0; it < 2; ++it)
        #pragma unroll
        for (int r = 0; r < 4; ++r) {
            int jr = idxbuf[wv][it][quad * 4 + r];
            const u16* vp = vb + (size_t)((bb << 12) + jr) * 64;
            #pragma unroll
            for (int nt = 0; nt < 4; ++nt)
                vpre[it][r][nt] = b2f(vp[nt * 16 + col]);
        }

    float rr[2][3];
    #pragma unroll
    for (int it = 0; it < 2; ++it) {
        rr[it][0] = relbuf[wv][it][m][0];
        rr[it][1] = relbuf[wv][it][m][1];
        rr[it][2] = relbuf[wv][it][m][2];
    }

    // t = relu(rel @ Wp1 + bp1), A-fragment layout, both queries (Wp1 shared).
    v8s a0[2], a1[2];
    #pragma unroll
    for (int hh = 0; hh < 2; ++hh) {
        int tb = hh * 32 + quad * 8;
        #pragma unroll
        for (int j = 0; j < 8; ++j) {
            float w0 = Wp1[0 * 64 + tb + j];
            float w1 = Wp1[1 * 64 + tb + j];
            float w2 = Wp1[2 * 64 + tb + j];
            float bp = bp1[tb + j];
            #pragma unroll
            for (int it = 0; it < 2; ++it) {
                float t = bp;
                t = fmaf(rr[it][0], w0, t);
                t = fmaf(rr[it][1], w1, t);
                t = fmaf(rr[it][2], w2, t);
                t = fmaxf(t, 0.0f);
                if (hh == 0) a0[it][j] = (short)f2b(t); else a1[it][j] = (short)f2b(t);
            }
        }
    }

    // pos = t @ Wp2 + bp2 (C-layout), both queries; vw = v + pos folded here.
    float vw[2][4][4];   // [it][r][nt]; the only long-lived state after this.
    #pragma unroll
    for (int nt = 0; nt < 4; ++nt) {
        float bias = bp2[nt * 16 + col];
        v8s bf0 = *(const v8s*)(wfrag + (0 + nt) * 512 + lane * 8);
        v8s bf1 = *(const v8s*)(wfrag + (4 + nt) * 512 + lane * 8);
        #pragma unroll
        for (int it = 0; it < 2; ++it) {
            v4f acc = {bias, bias, bias, bias};
            acc = __builtin_amdgcn_mfma_f32_16x16x32_bf16(a0[it], bf0, acc, 0, 0, 0);
            acc = __builtin_amdgcn_mfma_f32_16x16x32_bf16(a1[it], bf1, acc, 0, 0, 0);
            u16* pg = (u16*)&smem[wv][it][0];
            #pragma unroll
            for (int r = 0; r < 4; ++r) {
                pg[(quad * 4 + r) * 72 + nt * 16 + col] = f2b(acc[r]);
                vw[it][r][nt] = vpre[it][r][nt] + acc[r];
            }
        }
    }

    // h = q - k + pos in A-layout (bf16 inputs), both queries.
    v8s ha0[2], ha1[2];
    #pragma unroll
    for (int it = 0; it < 2; ++it) {
        int q = qbase + it;
        int jm = idxbuf[wv][it][m];
        const u16* qp = qb + (size_t)q * 64;
        const u16* kp = kb + (size_t)((bb << 12) + jm) * 64;
        const u16* pg = (const u16*)&smem[wv][it][0];
        #pragma unroll
        for (int hh = 0; hh < 2; ++hh) {
            int tb = hh * 32 + quad * 8;
            v8u qv = *(const v8u*)(qp + tb);
            v8u kv = *(const v8u*)(kp + tb);
            v8u pv = *(const v8u*)(pg + m * 72 + tb);
            #pragma unroll
            for (int j = 0; j < 8; ++j) {
                float hv = b2f(qv[j]) - b2f(kv[j]) + b2f(pv[j]);
                if (hh == 0) ha0[it][j] = (short)f2b(hv); else ha1[it][j] = (short)f2b(hv);
            }
        }
    }

    // g = relu(h @ Wm1 + bm1) -> pgbuf (bf16, C-layout scatter).
    // WAR on pgbuf vs pv reads above: same-wave program order -> safe.
    #pragma unroll
    for (int nt = 0; nt < 4; ++nt) {
        float bias = bm1[nt * 16 + col];
        v8s bf0 = *(const v8s*)(wfrag + 4096 + (0 + nt) * 512 + lane * 8);
        v8s bf1 = *(const v8s*)(wfrag + 4096 + (4 + nt) * 512 + lane * 8);
        #pragma unroll
        for (int it = 0; it < 2; ++it) {
            v4f acc = {bias, bias, bias, bias};
            acc = __builtin_amdgcn_mfma_f32_16x16x32_bf16(ha0[it], bf0, acc, 0, 0, 0);
            acc = __builtin_amdgcn_mfma_f32_16x16x32_bf16(ha1[it], bf1, acc, 0, 0, 0);
            u16* pg = (u16*)&smem[wv][it][0];
            #pragma unroll
            for (int r = 0; r < 4; ++r)
                pg[(quad * 4 + r) * 72 + nt * 16 + col] = f2b(fmaxf(acc[r], 0.0f));
        }
    }

    // ga fragments (bf16 vectors), both queries. pgbuf dead after this.
    v8s ga0[2], ga1[2];
    #pragma unroll
    for (int it = 0; it < 2; ++it) {
        const u16* pg = (const u16*)&smem[wv][it][0];
        ga0[it] = *(const v8s*)(pg + m * 72 + quad * 8);
        ga1[it] = *(const v8s*)(pg + m * 72 + 32 + quad * 8);
    }

    // att = g @ Wm2 + bm2, fused softmax; att values staged in LDS (f32)
    // over the dead pgbuf region for coalesced global write.
    float o4[2][4];
    #pragma unroll
    for (int nt = 0; nt < 4; ++nt) {
        float bias = bm2[nt * 16 + col];
        v8s bf0 = *(const v8s*)(wfrag + 8192 + (0 + nt) * 512 + lane * 8);
        v8s bf1 = *(const v8s*)(wfrag + 8192 + (4 + nt) * 512 + lane * 8);
        #pragma unroll
        for (int it = 0; it < 2; ++it) {
            v4f acc = {bias, bias, bias, bias};
            acc = __builtin_amdgcn_mfma_f32_16x16x32_bf16(ga0[it], bf0, acc, 0, 0, 0);
            acc = __builtin_amdgcn_mfma_f32_16x16x32_bf16(ga1[it], bf1, acc, 0, 0, 0);

            float s[4];
            #pragma unroll
            for (int r = 0; r < 4; ++r) s[r] = acc[r] * 0.125f;
            float mx = fmaxf(fmaxf(s[0], s[1]), fmaxf(s[2], s[3]));
            mx = fmaxf(mx, __shfl_xor(mx, 16, 64));
            mx = fmaxf(mx, __shfl_xor(mx, 32, 64));
            float e[4], sum = 0.0f;
            #pragma unroll
            for (int r = 0; r < 4; ++r) { e[r] = __expf(s[r] - mx); sum += e[r]; }
            sum += __shfl_xor(sum, 16, 64);
            sum += __shfl_xor(sum, 32, 64);
            float inv = 1.0f / sum;

            float o = 0.0f;
            #pragma unroll
            for (int r = 0; r < 4; ++r) {
                float a = e[r] * inv;
                smem[wv][it][(quad * 4 + r) * 64 + nt * 16 + col] = a;
                o = fmaf(a, vw[it][r][nt], o);
            }
            o += __shfl_xor(o, 16, 64);
            o += __shfl_xor(o, 32, 64);
            o4[it][nt] = o;
        }
    }
    // same-wave LDS handoff: all att ds_writes precede the reads below.

    // out_att: coalesced float4 stores, 1KB/instruction, each line once.
    #pragma unroll
    for (int it = 0; it < 2; ++it) {
        float* dst = out_att + (size_t)(qbase + it) * 1024;
        #pragma unroll
        for (int chunk = 0; chunk < 4; ++chunk) {
            float4 v4 = *(const float4*)&smem[wv][it][chunk * 256 + lane * 4];
            *(float4*)&dst[chunk * 256 + lane * 4] = v4;
        }
    }

    // obuf alias over dead att staging (reads above already in registers).
    #pragma unroll
    for (int it = 0; it < 2; ++it) {
        if (quad == 0) {
            #pragma unroll
            for (int nt = 0; nt < 4; ++nt) smem[wv][it][nt * 16 + col] = o4[it][nt];
        }
    }
    // same-wave LDS handoff: no barrier needed.

    // out = o @ W2 + b2 + features   (W2bt: bf16, transposed, L1/L2-hot);
    // w8 loaded once, shared by both queries. 4 partial accumulators break
    // the 64-deep dependent FMA chain (R17).
    const u16* wrow = wfrag + 3 * 4096 + lane * 64;
    v8u w8[8];
    #pragma unroll
    for (int c = 0; c < 8; ++c) w8[c] = *(const v8u*)(wrow + c * 8);
    #pragma unroll
    for (int it = 0; it < 2; ++it) {
        int q = qbase + it;
        const float* ob = &smem[wv][it][0];
        float p0 = 0.0f, p1 = 0.0f, p2 = 0.0f, p3 = 0.0f;
        #pragma unroll
        for (int g4 = 0; g4 < 4; ++g4) {
            #pragma unroll
            for (int cc = 0; cc < 4; ++cc) {
                int c = g4 * 4 + cc;
                float4 ov = *(const float4*)&ob[c * 4];
                float pp = (g4 == 0) ? p0 : (g4 == 1) ? p1 : (g4 == 2) ? p2 : p3;
                pp = fmaf(ov.x, b2f(w8[c >> 1][(c & 1) * 4 + 0]), pp);
                pp = fmaf(ov.y, b2f(w8[c >> 1][(c & 1) * 4 + 1]), pp);
                pp = fmaf(ov.z, b2f(w8[c >> 1][(c & 1) * 4 + 2]), pp);
                pp = fmaf(ov.w, b2f(w8[c >> 1][(c & 1) * 4 + 3]), pp);
                if (g4 == 0) p0 = pp; else if (g4 == 1) p1 = pp;
                else if (g4 == 2) p2 = pp; else p3 = pp;
            }
        }
        float base = b2[lane] + feats[(size_t)q * 64 + lane];
        out0[(size_t)q * 64 + lane] = base + ((p0 + p1) + (p2 + p3));
    }
}

// ---------------------------------------------------------------------------
extern "C" void kernel_launch(void* const* d_in, const int* in_sizes, int n_in,
                              void* d_out, int out_size, void* d_ws, size_t ws_size,
                              hipStream_t stream)
{
    (void)in_sizes; (void)n_in; (void)out_size; (void)ws_size;
    const float* coords = (const float*)d_in[0];
    const float* feats  = (const float*)d_in[1];
    const float* W1  = (const float*)d_in[2];
    const float* b1  = (const float*)d_in[3];
    const float* Wq  = (const float*)d_in[4];
    const float* Wk  = (const float*)d_in[5];
    const float* Wv  = (const float*)d_in[6];
    const float* Wm1 = (const float*)d_in[7];
    const float* bm1 = (const float*)d_in[8];
    const float* Wm2 = (const float*)d_in[9];
    const float* bm2 = (const float*)d_in[10];
    const float* Wp1 = (const float*)d_in[11];
    const float* bp1 = (const float*)d_in[12];
    const float* Wp2 = (const float*)d_in[13];
    const float* bp2 = (const float*)d_in[14];
    const float* W2  = (const float*)d_in[15];
    const float* b2  = (const float*)d_in[16];

    char* ws = (char*)d_ws;
    u16*    qb    = (u16*)(ws);
    u16*    kb    = (u16*)(ws + (4u << 20));
    u16*    vb    = (u16*)(ws + (8u << 20));
    float4* c4    = (float4*)(ws + (12u << 20));
    int*    knn   = (int*)(ws + (12u << 20) + (256u << 10));
    u16*    wfrag = (u16*)(ws + (12u << 20) + (256u << 10) + (1u << 20));

    float* out0    = (float*)d_out;
    float* out_att = out0 + (size_t)4 * 4096 * 64;

    prep_kernel<<<260, 256, 0, stream>>>(feats, coords, W1, b1, Wq, Wk, Wv,
                                         Wp2, Wm1, Wm2, W2,
                                         qb, kb, vb, c4, wfrag);
    knn_kernel<<<4096, 256, 0, stream>>>(c4, knn);
    attn_kernel<<<2048, 256, 0, stream>>>(qb, kb, vb, c4, knn, wfrag,
                                          Wp1, bp1, bp2, bm1, bm2, b2, feats,
                                          out0, out_att);
}